// Round 2
// baseline (897.993 us; speedup 1.0000x reference)
//
#include <hip/hip_runtime.h>
#include <hip/hip_bf16.h>

constexpr int Bn = 4, Nn = 2048, Dm = 128, Hh = 4;
constexpr int MN = Bn * Nn;              // 8192 rows
constexpr size_t SZ = (size_t)MN * Dm;   // 1,048,576 floats per [B,N,D] buffer

// ---------------- generic fused linear: C = [res+relu]( (A + sum extras) @ W + b ) ----------------
// A: f32 [M,128]; W: f32 [128,128]; C: f32 [M,128].
// If nextra>0: staged A-row = A + sum_e extra[e*estride + ...]  (attention partials)
// If relu_res: C = staged_A + relu(staged_A @ W + b)
__global__ void k_linear(const float* __restrict__ A,
                         const float* __restrict__ extra, int nextra, size_t estride,
                         const float* __restrict__ W, const float* __restrict__ bias,
                         int M, int relu_res, float* __restrict__ C) {
    __shared__ float4 lds4[16][32];
    float* ldsf = (float*)lds4;                  // [16][128]
    const int tid = threadIdx.x;
    const int m0 = blockIdx.x * 16;

    // stage 16x128 A tile (512 float4 slots, 256 threads -> 2 each)
    #pragma unroll
    for (int it = 0; it < 2; ++it) {
        int f = it * 256 + tid;
        int r = f >> 5, c = f & 31;
        int row = m0 + r;
        float4 v = make_float4(0.f, 0.f, 0.f, 0.f);
        if (row < M) {
            v = ((const float4*)(A + (size_t)row * Dm))[c];
            for (int e = 0; e < nextra; ++e) {
                float4 w = ((const float4*)(extra + (size_t)e * estride + (size_t)row * Dm))[c];
                v.x += w.x; v.y += w.y; v.z += w.z; v.w += w.w;
            }
        }
        lds4[r][c] = v;
    }
    __syncthreads();

    const int col = tid & 127;
    const int rg  = tid >> 7;                    // 0 or 1
    float acc[8] = {0.f,0.f,0.f,0.f,0.f,0.f,0.f,0.f};
    #pragma unroll 8
    for (int k = 0; k < 128; ++k) {
        float w = W[k * Dm + col];
        #pragma unroll
        for (int i = 0; i < 8; ++i)
            acc[i] = fmaf(ldsf[(rg + 2 * i) * Dm + k], w, acc[i]);
    }
    float bb = bias[col];
    #pragma unroll
    for (int i = 0; i < 8; ++i) {
        int r = rg + 2 * i;
        int row = m0 + r;
        if (row < M) {
            float v = acc[i] + bb;
            if (relu_res) v = fmaxf(v, 0.f) + ldsf[r * Dm + col];
            C[(size_t)row * Dm + col] = v;
        }
    }
}

// ---------------- sigmoid attention (SAB layers), m-split partials ----------------
// grid: (B*H, N/64, ms), block 64. Opart[ms][b,n,D] = sum_{m in slice} sigmoid(q.k/sqrt(128)) * v
__global__ void k_attn(const float* __restrict__ Qp, const float* __restrict__ Kp,
                       const float* __restrict__ Vp, float* __restrict__ Opart) {
    const int b = blockIdx.x >> 2, h = blockIdx.x & 3;
    const int n = blockIdx.y * 64 + threadIdx.x;
    const int msCount = gridDim.z;
    const int mlen = Nn / msCount;
    const int m0base = blockIdx.z * mlen;
    const size_t base = (size_t)b * Nn * Dm + h * 32;

    __shared__ float4 kt[64][8];
    __shared__ float4 vt[64][8];

    float4 q[8];
    {
        const float4* qp = (const float4*)(Qp + base + (size_t)n * Dm);
        #pragma unroll
        for (int i = 0; i < 8; ++i) q[i] = qp[i];
    }
    float4 acc[8];
    #pragma unroll
    for (int i = 0; i < 8; ++i) acc[i] = make_float4(0.f, 0.f, 0.f, 0.f);

    const float scale = 0.08838834764831845f;   // 1/sqrt(128)

    for (int mt = 0; mt < mlen; mt += 64) {
        const int m0 = m0base + mt;
        #pragma unroll
        for (int i = 0; i < 8; ++i) {
            int f = i * 64 + threadIdx.x;
            int r = f >> 3, c = f & 7;
            kt[r][c] = ((const float4*)(Kp + base + (size_t)(m0 + r) * Dm))[c];
            vt[r][c] = ((const float4*)(Vp + base + (size_t)(m0 + r) * Dm))[c];
        }
        __syncthreads();
        #pragma unroll 2
        for (int j = 0; j < 64; ++j) {
            float d0 = 0.f, d1 = 0.f, d2 = 0.f, d3 = 0.f;
            #pragma unroll
            for (int c = 0; c < 8; c += 4) {
                float4 k0 = kt[j][c+0], k1 = kt[j][c+1], k2 = kt[j][c+2], k3 = kt[j][c+3];
                d0 += q[c+0].x*k0.x + q[c+0].y*k0.y + q[c+0].z*k0.z + q[c+0].w*k0.w;
                d1 += q[c+1].x*k1.x + q[c+1].y*k1.y + q[c+1].z*k1.z + q[c+1].w*k1.w;
                d2 += q[c+2].x*k2.x + q[c+2].y*k2.y + q[c+2].z*k2.z + q[c+2].w*k2.w;
                d3 += q[c+3].x*k3.x + q[c+3].y*k3.y + q[c+3].z*k3.z + q[c+3].w*k3.w;
            }
            float dot = (d0 + d1) + (d2 + d3);
            float a = 1.f / (1.f + __expf(-dot * scale));
            #pragma unroll
            for (int c = 0; c < 8; ++c) {
                float4 vv = vt[j][c];
                acc[c].x = fmaf(a, vv.x, acc[c].x);
                acc[c].y = fmaf(a, vv.y, acc[c].y);
                acc[c].z = fmaf(a, vv.z, acc[c].z);
                acc[c].w = fmaf(a, vv.w, acc[c].w);
            }
        }
        __syncthreads();
    }
    float4* op = (float4*)(Opart + (size_t)blockIdx.z * SZ + base + (size_t)n * Dm);
    #pragma unroll
    for (int i = 0; i < 8; ++i) op[i] = acc[i];
}

// ---------------- PMA attention (nq=1): one block per (b,h) ----------------
// q = S @ Wq[:, h*32:+32] + bq  computed in-kernel; P0[b, h*32+d] = q[d] + sum_m sigmoid(q.k)*v
__global__ void k_pma(const float* __restrict__ S, const float* __restrict__ Wq, const float* __restrict__ bq,
                      const float* __restrict__ Kp, const float* __restrict__ Vp,
                      float* __restrict__ P0) {
    const int b = blockIdx.x >> 2, h = blockIdx.x & 3;
    const int tid = threadIdx.x;
    __shared__ float4 qs4[8];
    float* qs = (float*)qs4;
    if (tid < 32) {
        float a = bq[h * 32 + tid];
        for (int k = 0; k < 128; ++k)
            a = fmaf(S[k], Wq[k * Dm + h * 32 + tid], a);
        qs[tid] = a;
    }
    __syncthreads();

    float4 q[8];
    #pragma unroll
    for (int i = 0; i < 8; ++i) q[i] = qs4[i];
    float4 acc[8];
    #pragma unroll
    for (int i = 0; i < 8; ++i) acc[i] = make_float4(0.f, 0.f, 0.f, 0.f);

    const size_t base = (size_t)b * Nn * Dm + h * 32;
    const float scale = 0.08838834764831845f;

    for (int it = 0; it < Nn / 256; ++it) {
        int m = it * 256 + tid;
        const float4* kp = (const float4*)(Kp + base + (size_t)m * Dm);
        const float4* vp = (const float4*)(Vp + base + (size_t)m * Dm);
        float d0 = 0.f, d1 = 0.f, d2 = 0.f, d3 = 0.f;
        #pragma unroll
        for (int c = 0; c < 8; c += 4) {
            float4 k0 = kp[c+0], k1 = kp[c+1], k2 = kp[c+2], k3 = kp[c+3];
            d0 += q[c+0].x*k0.x + q[c+0].y*k0.y + q[c+0].z*k0.z + q[c+0].w*k0.w;
            d1 += q[c+1].x*k1.x + q[c+1].y*k1.y + q[c+1].z*k1.z + q[c+1].w*k1.w;
            d2 += q[c+2].x*k2.x + q[c+2].y*k2.y + q[c+2].z*k2.z + q[c+2].w*k2.w;
            d3 += q[c+3].x*k3.x + q[c+3].y*k3.y + q[c+3].z*k3.z + q[c+3].w*k3.w;
        }
        float dot = (d0 + d1) + (d2 + d3);
        float a = 1.f / (1.f + __expf(-dot * scale));
        #pragma unroll
        for (int c = 0; c < 8; ++c) {
            float4 vv = vp[c];
            acc[c].x = fmaf(a, vv.x, acc[c].x);
            acc[c].y = fmaf(a, vv.y, acc[c].y);
            acc[c].z = fmaf(a, vv.z, acc[c].z);
            acc[c].w = fmaf(a, vv.w, acc[c].w);
        }
    }
    // wave butterfly reduction (64 lanes)
    #pragma unroll
    for (int off = 1; off < 64; off <<= 1) {
        #pragma unroll
        for (int c = 0; c < 8; ++c) {
            acc[c].x += __shfl_xor(acc[c].x, off);
            acc[c].y += __shfl_xor(acc[c].y, off);
            acc[c].z += __shfl_xor(acc[c].z, off);
            acc[c].w += __shfl_xor(acc[c].w, off);
        }
    }
    __shared__ float red[4][32];
    const int wave = tid >> 6, lane = tid & 63;
    if (lane == 0) {
        #pragma unroll
        for (int c = 0; c < 8; ++c) {
            red[wave][c*4+0] = acc[c].x;
            red[wave][c*4+1] = acc[c].y;
            red[wave][c*4+2] = acc[c].z;
            red[wave][c*4+3] = acc[c].w;
        }
    }
    __syncthreads();
    if (tid < 32) {
        float t = red[0][tid] + red[1][tid] + red[2][tid] + red[3][tid];
        P0[b * Dm + h * 32 + tid] = qs[tid] + t;
    }
}

// ---------------- final projection: out[b,c] = P[b,:] @ pW + pb, f32 out ----------------
__global__ void k_final(const float* __restrict__ P, const float* __restrict__ pW,
                        const float* __restrict__ pb, float* __restrict__ out) {
    const int b = blockIdx.x, c = threadIdx.x;   // 256 threads
    __shared__ float ps[128];
    if (c < 128) ps[c] = P[b * Dm + c];
    __syncthreads();
    float a = pb[c];
    #pragma unroll 8
    for (int k = 0; k < 128; ++k)
        a = fmaf(ps[k], pW[k * 256 + c], a);
    out[b * 256 + c] = a;
}

extern "C" void kernel_launch(void* const* d_in, const int* in_sizes, int n_in,
                              void* d_out, int out_size, void* d_ws, size_t ws_size,
                              hipStream_t stream) {
    const float* X = (const float*)d_in[0];
    auto W = [&](int i) { return (const float*)d_in[i]; };
    float* ws = (float*)d_ws;

    // choose partial-count from available workspace: slots = 4 + ms, each SZ floats (4 MB)
    int slots_avail = (int)(ws_size / (SZ * sizeof(float)));
    int ms = slots_avail - 4;
    if (ms > 4) ms = 4;
    if (ms < 1) ms = 1;
    while ((Nn % ms) != 0) --ms;   // ms in {1,2,4} anyway

    // slot layout (each SZ floats = 4 MB):
    //   s0=Qp  s1=Kp  s2=Vp  s3..s(3+ms-1)=Opart  s(3+ms)=X1
    // reuse: X2 -> s1 (Kp dead), K2 -> s0, V2 -> s2, P0 -> s3, Pp -> s3+4096
    float* Qp    = ws + 0 * SZ;
    float* Kp    = ws + 1 * SZ;
    float* Vp    = ws + 2 * SZ;
    float* Opart = ws + 3 * SZ;              // ms contiguous partial buffers
    float* X1    = ws + (size_t)(3 + ms) * SZ;
    float* X2    = Kp;                        // overwrite dead Kp after layer-1 attention
    float* K2    = Qp;
    float* V2    = Vp;
    float* P0    = Opart;                     // 512 floats
    float* Pp    = Opart + 4096;              // 512 floats, disjoint from P0

    const int GL = (MN + 15) / 16;            // 512 blocks for M=8192
    dim3 attn_grid(Bn * Hh, Nn / 64, ms);

    // ---- SAB layer 0 (weights 1..8) ----
    k_linear<<<GL, 256, 0, stream>>>(X, nullptr, 0, 0, W(1), W(2), MN, 0, Qp);
    k_linear<<<GL, 256, 0, stream>>>(X, nullptr, 0, 0, W(3), W(4), MN, 0, Kp);
    k_linear<<<GL, 256, 0, stream>>>(X, nullptr, 0, 0, W(5), W(6), MN, 0, Vp);
    k_attn<<<attn_grid, 64, 0, stream>>>(Qp, Kp, Vp, Opart);
    k_linear<<<GL, 256, 0, stream>>>(Qp, Opart, ms, SZ, W(7), W(8), MN, 1, X1);

    // ---- SAB layer 1 (weights 9..16) ----
    k_linear<<<GL, 256, 0, stream>>>(X1, nullptr, 0, 0, W(9),  W(10), MN, 0, Qp);
    k_linear<<<GL, 256, 0, stream>>>(X1, nullptr, 0, 0, W(11), W(12), MN, 0, Kp);
    k_linear<<<GL, 256, 0, stream>>>(X1, nullptr, 0, 0, W(13), W(14), MN, 0, Vp);
    k_attn<<<attn_grid, 64, 0, stream>>>(Qp, Kp, Vp, Opart);
    k_linear<<<GL, 256, 0, stream>>>(Qp, Opart, ms, SZ, W(15), W(16), MN, 1, X2);

    // ---- PMA (weights 17..24, S=25) ----
    k_linear<<<GL, 256, 0, stream>>>(X2, nullptr, 0, 0, W(19), W(20), MN, 0, K2);
    k_linear<<<GL, 256, 0, stream>>>(X2, nullptr, 0, 0, W(21), W(22), MN, 0, V2);
    k_pma<<<Bn * Hh, 256, 0, stream>>>((const float*)d_in[25], W(17), W(18), K2, V2, P0);
    k_linear<<<1, 256, 0, stream>>>(P0, nullptr, 0, 0, W(23), W(24), Bn, 1, Pp);

    // ---- final projection (pW=26, pb=27) ----
    k_final<<<Bn, 256, 0, stream>>>(Pp, (const float*)d_in[26], (const float*)d_in[27], (float*)d_out);
}

// Round 3
// 363.204 us; speedup vs baseline: 2.4724x; 2.4724x over previous
//
#include <hip/hip_runtime.h>
#include <hip/hip_bf16.h>

typedef __hip_bfloat16 HB;
typedef __attribute__((ext_vector_type(8))) short short8;
typedef __attribute__((ext_vector_type(4))) short short4v;
typedef __attribute__((ext_vector_type(4))) float f32x4;

constexpr int Bn = 4, Nn = 2048, Dm = 128, Hh = 4;
constexpr int MN = Bn * Nn;              // 8192 rows
constexpr size_t SZ = (size_t)MN * Dm;   // 1,048,576 elems per [B,N,128] buffer

static __device__ __forceinline__ short f2bs(float x) {
    __hip_bfloat16 h = __float2bfloat16(x);
    return __builtin_bit_cast(short, h);
}

// ---------------- generic fused linear (UNCHANGED from passing R2) ----------------
__global__ void k_linear(const float* __restrict__ A,
                         const float* __restrict__ extra, int nextra, size_t estride,
                         const float* __restrict__ W, const float* __restrict__ bias,
                         int M, int relu_res, float* __restrict__ C) {
    __shared__ float4 lds4[16][32];
    float* ldsf = (float*)lds4;                  // [16][128]
    const int tid = threadIdx.x;
    const int m0 = blockIdx.x * 16;

    #pragma unroll
    for (int it = 0; it < 2; ++it) {
        int f = it * 256 + tid;
        int r = f >> 5, c = f & 31;
        int row = m0 + r;
        float4 v = make_float4(0.f, 0.f, 0.f, 0.f);
        if (row < M) {
            v = ((const float4*)(A + (size_t)row * Dm))[c];
            for (int e = 0; e < nextra; ++e) {
                float4 w = ((const float4*)(extra + (size_t)e * estride + (size_t)row * Dm))[c];
                v.x += w.x; v.y += w.y; v.z += w.z; v.w += w.w;
            }
        }
        lds4[r][c] = v;
    }
    __syncthreads();

    const int col = tid & 127;
    const int rg  = tid >> 7;
    float acc[8] = {0.f,0.f,0.f,0.f,0.f,0.f,0.f,0.f};
    #pragma unroll 8
    for (int k = 0; k < 128; ++k) {
        float w = W[k * Dm + col];
        #pragma unroll
        for (int i = 0; i < 8; ++i)
            acc[i] = fmaf(ldsf[(rg + 2 * i) * Dm + k], w, acc[i]);
    }
    float bb = bias[col];
    #pragma unroll
    for (int i = 0; i < 8; ++i) {
        int r = rg + 2 * i;
        int row = m0 + r;
        if (row < M) {
            float v = acc[i] + bb;
            if (relu_res) v = fmaxf(v, 0.f) + ldsf[r * Dm + col];
            C[(size_t)row * Dm + col] = v;
        }
    }
}

// ---------------- f32 -> bf16 elementwise ----------------
__global__ void k_cvt_bf(const float* __restrict__ in, HB* __restrict__ out, int n) {
    int i = (blockIdx.x * 256 + threadIdx.x) * 4;
    if (i + 3 < n) {
        float4 v = *(const float4*)(in + i);
        short4v p;
        p[0] = f2bs(v.x); p[1] = f2bs(v.y); p[2] = f2bs(v.z); p[3] = f2bs(v.w);
        *(short4v*)((short*)out + i) = p;
    }
}

// ---------------- V transpose+convert: Vp f32 [B,N,128] -> Vt bf16 [16 bh][32 dh][2048 n] ----------------
__global__ void k_vt(const float* __restrict__ Vp, HB* __restrict__ Vt) {
    const int bh = blockIdx.x, b = bh >> 2, h = bh & 3;
    const int n0 = blockIdx.y * 64;
    __shared__ float t[64][33];
    const int tid = threadIdx.x;
    #pragma unroll
    for (int it = 0; it < 2; ++it) {
        int f = it * 256 + tid;
        int r = f >> 3, c4 = f & 7;
        float4 v = *(const float4*)(Vp + (size_t)(b * Nn + n0 + r) * Dm + h * 32 + c4 * 4);
        t[r][c4 * 4 + 0] = v.x; t[r][c4 * 4 + 1] = v.y;
        t[r][c4 * 4 + 2] = v.z; t[r][c4 * 4 + 3] = v.w;
    }
    __syncthreads();
    const int c = tid >> 3, n8 = tid & 7;
    short8 p;
    #pragma unroll
    for (int k = 0; k < 8; ++k) p[k] = f2bs(t[n8 * 8 + k][c]);
    *(short8*)((short*)Vt + (size_t)(bh * 32 + c) * Nn + n0 + n8 * 8) = p;
}

// ---------------- MFMA sigmoid attention ----------------
// grid: 16 bh * 64 qg blocks, 256 thr (4 waves). Wave w: 32 q rows (qg*32..+32), m-range [w*512, w*512+512).
// Opart[w][b,n,128(head-packed)] = sum_{m in slice} sigmoid(q.k/sqrt(128)) * v   (fp32)
__global__ void k_attn2(const float* __restrict__ Qp, const HB* __restrict__ Kbf,
                        const HB* __restrict__ Vt, float* __restrict__ Opart) {
    const int tid = threadIdx.x;
    const int w = tid >> 6, lane = tid & 63, l15 = lane & 15, quad = lane >> 4;
    const int bh = blockIdx.x >> 6, qg = blockIdx.x & 63;
    const int b = bh >> 2, h = bh & 3;

    __shared__ __align__(16) HB sbuf[4][2][16][72];   // per-wave S tile, pitch 72 bf16 (16B-aligned rows)

    const float scale = 0.08838834764831845f;   // 1/sqrt(128)

    // Q A-frags: A[q=l15][k=dh=quad*8+j], read fp32, cvt to bf16
    short8 aq[2];
    #pragma unroll
    for (int qa = 0; qa < 2; ++qa) {
        const float* qp = Qp + (size_t)(b * Nn + qg * 32 + qa * 16 + l15) * Dm + h * 32 + quad * 8;
        float4 q0 = *(const float4*)qp;
        float4 q1 = *(const float4*)(qp + 4);
        short8 t;
        t[0] = f2bs(q0.x); t[1] = f2bs(q0.y); t[2] = f2bs(q0.z); t[3] = f2bs(q0.w);
        t[4] = f2bs(q1.x); t[5] = f2bs(q1.y); t[6] = f2bs(q1.z); t[7] = f2bs(q1.w);
        aq[qa] = t;
    }

    f32x4 zero = {0.f, 0.f, 0.f, 0.f};
    f32x4 o[2][2];
    #pragma unroll
    for (int qa = 0; qa < 2; ++qa)
        #pragma unroll
        for (int t = 0; t < 2; ++t) o[qa][t] = zero;

    const short* Kb = (const short*)Kbf + (size_t)b * Nn * Dm + h * 32;
    const short* Vb = (const short*)Vt + (size_t)bh * 32 * Nn;

    for (int m0 = w * 512; m0 < w * 512 + 512; m0 += 64) {
        // K B-frags: B[k=dh=quad*8+j][n=m'=l15] = K[m0+mc*16+l15][dh]
        short8 kb[4];
        #pragma unroll
        for (int mc = 0; mc < 4; ++mc)
            kb[mc] = *(const short8*)(Kb + (size_t)(m0 + mc * 16 + l15) * Dm + quad * 8);
        // V B-frags: B[k=m-local=quad*8+j][n=dh-local=l15] = Vt[t*16+l15][m0+u*32+quad*8+j]
        short8 vb[2][2];
        #pragma unroll
        for (int t = 0; t < 2; ++t)
            #pragma unroll
            for (int u = 0; u < 2; ++u)
                vb[t][u] = *(const short8*)(Vb + (size_t)(t * 16 + l15) * Nn + m0 + u * 32 + quad * 8);

        // S = Q K^T  (D[q][m']: row=q=quad*4+r, col=m'=l15 within 16-chunk mc)
        f32x4 s[2][4];
        #pragma unroll
        for (int qa = 0; qa < 2; ++qa)
            #pragma unroll
            for (int mc = 0; mc < 4; ++mc)
                s[qa][mc] = __builtin_amdgcn_mfma_f32_16x16x32_bf16(aq[qa], kb[mc], zero, 0, 0, 0);

        // sigmoid -> bf16 -> LDS (C-layout write)
        #pragma unroll
        for (int qa = 0; qa < 2; ++qa)
            #pragma unroll
            for (int mc = 0; mc < 4; ++mc)
                #pragma unroll
                for (int r = 0; r < 4; ++r) {
                    float sg = 1.0f / (1.0f + __expf(-s[qa][mc][r] * scale));
                    sbuf[w][qa][quad * 4 + r][mc * 16 + l15] = __float2bfloat16(sg);
                }

        // read back as A-frags: A[q=l15][k=m-local=quad*8+j] (same-wave RAW, lgkmcnt-ordered)
        short8 as2[2][2];
        #pragma unroll
        for (int qa = 0; qa < 2; ++qa)
            #pragma unroll
            for (int u = 0; u < 2; ++u)
                as2[qa][u] = *(const short8*)((const short*)&sbuf[w][qa][l15][0] + u * 32 + quad * 8);

        // O += S V
        #pragma unroll
        for (int qa = 0; qa < 2; ++qa)
            #pragma unroll
            for (int t = 0; t < 2; ++t)
                #pragma unroll
                for (int u = 0; u < 2; ++u)
                    o[qa][t] = __builtin_amdgcn_mfma_f32_16x16x32_bf16(as2[qa][u], vb[t][u], o[qa][t], 0, 0, 0);
    }

    #pragma unroll
    for (int qa = 0; qa < 2; ++qa)
        #pragma unroll
        for (int t = 0; t < 2; ++t)
            #pragma unroll
            for (int r = 0; r < 4; ++r)
                Opart[(size_t)w * SZ + (size_t)(b * Nn + qg * 32 + qa * 16 + quad * 4 + r) * Dm
                      + h * 32 + t * 16 + l15] = o[qa][t][r];
}

// ---------------- PMA attention (UNCHANGED from passing R2) ----------------
__global__ void k_pma(const float* __restrict__ S, const float* __restrict__ Wq, const float* __restrict__ bq,
                      const float* __restrict__ Kp, const float* __restrict__ Vp,
                      float* __restrict__ P0) {
    const int b = blockIdx.x >> 2, h = blockIdx.x & 3;
    const int tid = threadIdx.x;
    __shared__ float4 qs4[8];
    float* qs = (float*)qs4;
    if (tid < 32) {
        float a = bq[h * 32 + tid];
        for (int k = 0; k < 128; ++k)
            a = fmaf(S[k], Wq[k * Dm + h * 32 + tid], a);
        qs[tid] = a;
    }
    __syncthreads();

    float4 q[8];
    #pragma unroll
    for (int i = 0; i < 8; ++i) q[i] = qs4[i];
    float4 acc[8];
    #pragma unroll
    for (int i = 0; i < 8; ++i) acc[i] = make_float4(0.f, 0.f, 0.f, 0.f);

    const size_t base = (size_t)b * Nn * Dm + h * 32;
    const float scale = 0.08838834764831845f;

    for (int it = 0; it < Nn / 256; ++it) {
        int m = it * 256 + tid;
        const float4* kp = (const float4*)(Kp + base + (size_t)m * Dm);
        const float4* vp = (const float4*)(Vp + base + (size_t)m * Dm);
        float d0 = 0.f, d1 = 0.f, d2 = 0.f, d3 = 0.f;
        #pragma unroll
        for (int c = 0; c < 8; c += 4) {
            float4 k0 = kp[c+0], k1 = kp[c+1], k2 = kp[c+2], k3 = kp[c+3];
            d0 += q[c+0].x*k0.x + q[c+0].y*k0.y + q[c+0].z*k0.z + q[c+0].w*k0.w;
            d1 += q[c+1].x*k1.x + q[c+1].y*k1.y + q[c+1].z*k1.z + q[c+1].w*k1.w;
            d2 += q[c+2].x*k2.x + q[c+2].y*k2.y + q[c+2].z*k2.z + q[c+2].w*k2.w;
            d3 += q[c+3].x*k3.x + q[c+3].y*k3.y + q[c+3].z*k3.z + q[c+3].w*k3.w;
        }
        float dot = (d0 + d1) + (d2 + d3);
        float a = 1.f / (1.f + __expf(-dot * scale));
        #pragma unroll
        for (int c = 0; c < 8; ++c) {
            float4 vv = vp[c];
            acc[c].x = fmaf(a, vv.x, acc[c].x);
            acc[c].y = fmaf(a, vv.y, acc[c].y);
            acc[c].z = fmaf(a, vv.z, acc[c].z);
            acc[c].w = fmaf(a, vv.w, acc[c].w);
        }
    }
    #pragma unroll
    for (int off = 1; off < 64; off <<= 1) {
        #pragma unroll
        for (int c = 0; c < 8; ++c) {
            acc[c].x += __shfl_xor(acc[c].x, off);
            acc[c].y += __shfl_xor(acc[c].y, off);
            acc[c].z += __shfl_xor(acc[c].z, off);
            acc[c].w += __shfl_xor(acc[c].w, off);
        }
    }
    __shared__ float red[4][32];
    const int wave = tid >> 6, lane = tid & 63;
    if (lane == 0) {
        #pragma unroll
        for (int c = 0; c < 8; ++c) {
            red[wave][c*4+0] = acc[c].x;
            red[wave][c*4+1] = acc[c].y;
            red[wave][c*4+2] = acc[c].z;
            red[wave][c*4+3] = acc[c].w;
        }
    }
    __syncthreads();
    if (tid < 32) {
        float t = red[0][tid] + red[1][tid] + red[2][tid] + red[3][tid];
        P0[b * Dm + h * 32 + tid] = qs[tid] + t;
    }
}

// ---------------- final projection ----------------
__global__ void k_final(const float* __restrict__ P, const float* __restrict__ pW,
                        const float* __restrict__ pb, float* __restrict__ out) {
    const int b = blockIdx.x, c = threadIdx.x;
    __shared__ float ps[128];
    if (c < 128) ps[c] = P[b * Dm + c];
    __syncthreads();
    float a = pb[c];
    #pragma unroll 8
    for (int k = 0; k < 128; ++k)
        a = fmaf(ps[k], pW[k * 256 + c], a);
    out[b * 256 + c] = a;
}

extern "C" void kernel_launch(void* const* d_in, const int* in_sizes, int n_in,
                              void* d_out, int out_size, void* d_ws, size_t ws_size,
                              hipStream_t stream) {
    const float* X = (const float*)d_in[0];
    auto W = [&](int i) { return (const float*)d_in[i]; };
    float* ws = (float*)d_ws;

    // 8 slots of SZ floats (4 MB) = 32 MB total:
    //   s0: Qp(L0) -> X1 (in-place) -> K2
    //   s1: Kp(L0) -> Qp(L1) -> X2 (in-place)
    //   s2: Vp(L0) -> Vp(L1) -> V2
    //   s3..s6: Opart x4   (s3 also transiently Kp(L1); P0/Pp at the end)
    //   s7: Kbf (2MB) + Vt (2MB), bf16
    float* s0    = ws + 0 * SZ;
    float* s1    = ws + 1 * SZ;
    float* s2    = ws + 2 * SZ;
    float* Opart = ws + 3 * SZ;
    HB*    Kbf   = (HB*)(ws + 7 * SZ);
    HB*    Vt    = (HB*)(ws + 7 * SZ) + SZ;
    float* P0    = Opart;
    float* Pp    = Opart + 4096;

    const int GL = MN / 16;                   // 512 blocks
    const int GC = (int)(SZ / 4 / 256);       // 1024 blocks for cvt
    dim3 vt_grid(Bn * Hh, Nn / 64);
    const int attn_blocks = Bn * Hh * (Nn / 32);   // 16 * 64 = 1024

    // ---- SAB layer 0 (weights 1..8) ----
    k_linear<<<GL, 256, 0, stream>>>(X, nullptr, 0, 0, W(1), W(2), MN, 0, s0);   // Qp
    k_linear<<<GL, 256, 0, stream>>>(X, nullptr, 0, 0, W(3), W(4), MN, 0, s1);   // Kp
    k_linear<<<GL, 256, 0, stream>>>(X, nullptr, 0, 0, W(5), W(6), MN, 0, s2);   // Vp
    k_cvt_bf<<<GC, 256, 0, stream>>>(s1, Kbf, (int)SZ);
    k_vt<<<vt_grid, 256, 0, stream>>>(s2, Vt);
    k_attn2<<<attn_blocks, 256, 0, stream>>>(s0, Kbf, Vt, Opart);
    k_linear<<<GL, 256, 0, stream>>>(s0, Opart, 4, SZ, W(7), W(8), MN, 1, s0);   // X1 in-place

    // ---- SAB layer 1 (weights 9..16) ----
    k_linear<<<GL, 256, 0, stream>>>(s0, nullptr, 0, 0, W(9),  W(10), MN, 0, s1);     // Qp(L1)
    k_linear<<<GL, 256, 0, stream>>>(s0, nullptr, 0, 0, W(11), W(12), MN, 0, Opart);  // Kp(L1) in s3
    k_linear<<<GL, 256, 0, stream>>>(s0, nullptr, 0, 0, W(13), W(14), MN, 0, s2);     // Vp(L1)
    k_cvt_bf<<<GC, 256, 0, stream>>>(Opart, Kbf, (int)SZ);
    k_vt<<<vt_grid, 256, 0, stream>>>(s2, Vt);
    k_attn2<<<attn_blocks, 256, 0, stream>>>(s1, Kbf, Vt, Opart);
    k_linear<<<GL, 256, 0, stream>>>(s1, Opart, 4, SZ, W(15), W(16), MN, 1, s1);      // X2 in-place

    // ---- PMA (weights 17..24, S=25) ----
    k_linear<<<GL, 256, 0, stream>>>(s1, nullptr, 0, 0, W(19), W(20), MN, 0, s0);     // K2
    k_linear<<<GL, 256, 0, stream>>>(s1, nullptr, 0, 0, W(21), W(22), MN, 0, s2);     // V2
    k_pma<<<Bn * Hh, 256, 0, stream>>>((const float*)d_in[25], W(17), W(18), s0, s2, P0);
    k_linear<<<1, 256, 0, stream>>>(P0, nullptr, 0, 0, W(23), W(24), Bn, 1, Pp);

    // ---- final projection (pW=26, pb=27) ----
    k_final<<<Bn, 256, 0, stream>>>(Pp, (const float*)d_in[26], (const float*)d_in[27], (float*)d_out);
}